// Round 4
// baseline (159.684 us; speedup 1.0000x reference)
//
#include <hip/hip_runtime.h>
#include <hip/hip_bf16.h>

#define BB 8
#define CC 128
#define HH 64
#define WW 64
#define OO 128
#define NJ 18
#define HW 4096

typedef unsigned short u16;
typedef unsigned int u32;
typedef __attribute__((ext_vector_type(8))) __bf16 bf16x8;
typedef __attribute__((ext_vector_type(4))) float f32x4;

__device__ __forceinline__ u16 f2bf(float f) {
    u32 u = __float_as_uint(f);
    u += 0x7fffu + ((u >> 16) & 1u);   // RNE
    return (u16)(u >> 16);
}
__device__ __forceinline__ float bflo(u32 u) { return __uint_as_float(u << 16); }
__device__ __forceinline__ float bfhi(u32 u) { return __uint_as_float(u & 0xffff0000u); }
__device__ __forceinline__ u32 pk2bf(float s0, float s1) {
    union { __hip_bfloat162 h; u32 u; } cv;
    cv.h = __float22bfloat162_rn(make_float2(s0, s1));   // v_cvt_pk_bf16_f32
    return cv.u;
}

// ---------------------------------------------------------------------------
// k_xT: x[b][c][hw] fp32 -> xT[b][hw][c] bf16. tile[64 hw][129 c-pad]:
// writes conflict-free (bank = (hw + c) % 32, c wave-uniform), reads 4-way
// (acceptable; kernel is HBM-bound).
// ---------------------------------------------------------------------------
__global__ __launch_bounds__(256)
void k_xT(const float* __restrict__ x, u16* __restrict__ xT) {
    __shared__ float tile[64][129];
    const int t = threadIdx.x;
    const int b = blockIdx.x >> 6;
    const int hw0 = (blockIdx.x & 63) << 6;
    const float* xb = x + (size_t)b * CC * HW + hw0;
    const int tw = t & 63, tc = t >> 6;
#pragma unroll
    for (int r = 0; r < 32; ++r) {
        int c = r * 4 + tc;                 // wave-uniform
        tile[tw][c] = xb[c * HW + tw];
    }
    __syncthreads();
    u16* dst = xT + ((size_t)b * HW + hw0) * CC;
#pragma unroll
    for (int r = 0; r < 4; ++r) {
        int item = t + (r << 8);            // 1024 items = 64 hw x 16 segs
        int seg = item & 15, hw = item >> 4;
        union { u32 d[4]; uint4 v; } p;
#pragma unroll
        for (int i = 0; i < 4; ++i)
            p.d[i] = pk2bf(tile[hw][seg * 8 + 2 * i], tile[hw][seg * 8 + 2 * i + 1]);
        *(uint4*)&dst[hw * CC + seg * 8] = p.v;
    }
}

// ---------------------------------------------------------------------------
// k_prep: wT[kk][o][c] bf16 and wA[j][q*128+c] bf16 (j padded to 32 w/ zeros).
// ---------------------------------------------------------------------------
__global__ void k_prep(const float* __restrict__ w_def,
                       const float* __restrict__ w_off,
                       u16* __restrict__ wT, u16* __restrict__ wA) {
    int idx = blockIdx.x * 256 + threadIdx.x;
    if (idx < 9 * OO * CC) {
        int c = idx & 127, o = (idx >> 7) & 127, kk = idx >> 14;
        wT[idx] = f2bf(w_def[(o * CC + c) * 9 + kk]);
    }
    if (idx < 32 * 1152) {
        int k = idx % 1152, j = idx / 1152;
        int q = k >> 7, c = k & 127;
        wA[idx] = (j < NJ) ? f2bf(w_off[(j * CC + c) * 9 + q]) : (u16)0;
    }
}

// ---------------------------------------------------------------------------
// k_off: offset conv via MFMA, M=18(->32), N=64, K=1152. XCD-swizzled:
// b = blockIdx & 7 keeps each batch's xT slice in one XCD L2.
// ---------------------------------------------------------------------------
__global__ __launch_bounds__(256, 2)
void k_off(const u16* __restrict__ xT, const u16* __restrict__ wA,
           const float* __restrict__ b_off, float* __restrict__ offs) {
    __shared__ u16 s_x[198 * 128];   // [3 rows x 66 w][128 c] swizzled
    const int t = threadIdx.x, lane = t & 63, wv = t >> 6;
    const int posl = lane & 15, kg = lane >> 4;
    const int b = blockIdx.x & 7, h = blockIdx.x >> 3;

    for (int it = t; it < 3168; it += 256) {
        int seg = it & 15, pix = it >> 4;       // pix = r*66 + wp
        int r = pix / 66, wp = pix - r * 66;
        int y = h - 1 + r, w = wp - 1;
        uint4 v = make_uint4(0, 0, 0, 0);
        if (y >= 0 && y < HH && w >= 0 && w < WW)
            v = *(const uint4*)&xT[((size_t)(b * HW) + y * WW + w) * CC + seg * 8];
        *(uint4*)&s_x[pix * 128 + ((seg ^ (pix & 15)) * 8)] = v;
    }
    __syncthreads();

    f32x4 acc0 = {0.f, 0.f, 0.f, 0.f}, acc1 = {0.f, 0.f, 0.f, 0.f};
    for (int q = 0; q < 9; ++q) {
        int qy = q / 3, qx = q - qy * 3;
        int pix = qy * 66 + (wv * 16 + posl) + qx;
        int prow = pix * 128, pxor = pix & 15;
#pragma unroll
        for (int ki = 0; ki < 4; ++ki) {
            int ks = q * 4 + ki;
            int cidx = ki * 4 + kg;
            bf16x8 bfr = *(const bf16x8*)&s_x[prow + ((cidx ^ pxor) * 8)];
            bf16x8 a0 = *(const bf16x8*)&wA[posl * 1152 + ks * 32 + kg * 8];
            bf16x8 a1 = *(const bf16x8*)&wA[(16 + posl) * 1152 + ks * 32 + kg * 8];
            acc0 = __builtin_amdgcn_mfma_f32_16x16x32_bf16(a0, bfr, acc0, 0, 0, 0);
            acc1 = __builtin_amdgcn_mfma_f32_16x16x32_bf16(a1, bfr, acc1, 0, 0, 0);
        }
    }
    const int pos = wv * 16 + posl;
#pragma unroll
    for (int r = 0; r < 4; ++r) {
        int j = kg * 4 + r;
        offs[(b * NJ + j) * HW + h * WW + pos] = acc0[r] + b_off[j];
    }
#pragma unroll
    for (int r = 0; r < 4; ++r) {
        int j = 16 + kg * 4 + r;
        if (j < NJ) offs[(b * NJ + j) * HW + h * WW + pos] = acc1[r] + b_off[j];
    }
}

// ---------------------------------------------------------------------------
// k_main: fused bilinear sample + bf16 MFMA GEMM.
// Block = (b, h row): N=64 pos, M=128 o, 256 threads / 4 waves, 3 blocks/CU.
// XCD swizzle b = blockIdx & 7. Per kk:
//   - coords per-lane in REGISTERS (pos = lane) — no LDS, no barrier
//   - gathers: 4 corners x 4 contiguous uint4 (one 64B line per corner)
//   - interp fp32 -> s_samp[seg][pos] (row 1040 B; stride 260 dw = 4 mod 32
//     -> conflict-free writes AND b128 frag reads)
//   - s_wt staged per kk, XOR swizzle (conflict-free, verified pattern)
//   - 32 MFMAs/wave (4 ksteps x 8 mtiles), 2 barriers/kk
// ---------------------------------------------------------------------------
__global__ __launch_bounds__(256, 3)
void k_main(const u16* __restrict__ xT, const float* __restrict__ offs,
            const u16* __restrict__ wT, const float* __restrict__ b_def,
            float* __restrict__ out) {
    __shared__ u16 s_wt[128 * 128];      // 32 KB, XOR-swizzled [o][c]
    __shared__ u16 s_samp[16 * 520];     // 16.25 KB, [seg][pos*8, pad 8]

    const int t = threadIdx.x, lane = t & 63, wv = t >> 6;
    const int posl = lane & 15, rg = lane >> 4;
    const int b = blockIdx.x & 7;
    const int h = blockIdx.x >> 3;
    const int w = lane;                   // gather position = lane
    const char* xb = (const char*)xT + (size_t)b * (HW * CC * 2);

    f32x4 acc[8];
#pragma unroll
    for (int mt = 0; mt < 8; ++mt) acc[mt] = (f32x4){0.f, 0.f, 0.f, 0.f};

    for (int kk = 0; kk < 9; ++kk) {
        // ---- stage weight slice (coalesced uint4 -> swizzled LDS) ----
#pragma unroll
        for (int r = 0; r < 8; ++r) {
            int item = r * 256 + t;
            int o = item >> 4, sg = item & 15;
            *(uint4*)&s_wt[o * 128 + ((sg ^ (o & 15)) * 8)] =
                *(const uint4*)&wT[kk * (OO * CC) + item * 8];
        }
        // ---- per-lane coords ----
        int ky = kk / 3, kx = kk - ky * 3;
        float oy = offs[(b * NJ + 2 * kk) * HW + h * WW + w];
        float ox = offs[(b * NJ + 2 * kk + 1) * HW + h * WW + w];
        float py = (float)(h - 1 + ky) + oy;
        float px = (float)(w - 1 + kx) + ox;
        float fy = floorf(py), fx = floorf(px);
        int iy0 = (int)fy, ix0 = (int)fx;
        float wy = py - fy, wx = px - fx;
        int iy1 = iy0 + 1, ix1 = ix0 + 1;
        float my0 = (iy0 >= 0 && iy0 < HH) ? 1.0f : 0.0f;
        float my1 = (iy1 >= 0 && iy1 < HH) ? 1.0f : 0.0f;
        float mx0 = (ix0 >= 0 && ix0 < WW) ? 1.0f : 0.0f;
        float mx1 = (ix1 >= 0 && ix1 < WW) ? 1.0f : 0.0f;
        int iy0c = min(max(iy0, 0), HH - 1), iy1c = min(max(iy1, 0), HH - 1);
        int ix0c = min(max(ix0, 0), WW - 1), ix1c = min(max(ix1, 0), WW - 1);
        float wy1 = 1.0f - wy, wx1 = 1.0f - wx;
        float cwx = my0 * mx0 * wy1 * wx1, cwy = my0 * mx1 * wy1 * wx;
        float cwz = my1 * mx0 * wy * wx1,  cww = my1 * mx1 * wy * wx;
        int cox = (iy0c * WW + ix0c) << 8, coy = (iy0c * WW + ix1c) << 8;
        int coz = (iy1c * WW + ix0c) << 8, cow = (iy1c * WW + ix1c) << 8;

        // ---- gather + interp: segs 4wv..4wv+3, pos = lane ----
#pragma unroll
        for (int j = 0; j < 4; ++j) {
            const int seg = 4 * wv + j;
            const char* base = xb + seg * 16;
            uint4 q00 = *(const uint4*)(base + cox);
            uint4 q01 = *(const uint4*)(base + coy);
            uint4 q10 = *(const uint4*)(base + coz);
            uint4 q11 = *(const uint4*)(base + cow);
            const u32* u00 = (const u32*)&q00;
            const u32* u01 = (const u32*)&q01;
            const u32* u10 = (const u32*)&q10;
            const u32* u11 = (const u32*)&q11;
            union { u32 d[4]; uint4 v; } p;
#pragma unroll
            for (int i = 0; i < 4; ++i) {
                float s0 = cwx * bflo(u00[i]) + cwy * bflo(u01[i])
                         + cwz * bflo(u10[i]) + cww * bflo(u11[i]);
                float s1 = cwx * bfhi(u00[i]) + cwy * bfhi(u01[i])
                         + cwz * bfhi(u10[i]) + cww * bfhi(u11[i]);
                p.d[i] = pk2bf(s0, s1);
            }
            *(uint4*)&s_samp[seg * 520 + lane * 8] = p.v;
        }
        __syncthreads();

        // ---- 32 MFMAs: 4 ksteps x 8 mtiles, wave wv = ntile wv ----
#pragma unroll
        for (int ct = 0; ct < 4; ++ct) {
            const int cidx = ct * 4 + rg;
            bf16x8 bfr = *(const bf16x8*)&s_samp[cidx * 520 + (wv * 16 + posl) * 8];
#pragma unroll
            for (int mt = 0; mt < 8; ++mt) {
                bf16x8 af = *(const bf16x8*)&s_wt[(mt * 16 + posl) * 128 + ((cidx ^ posl) * 8)];
                acc[mt] = __builtin_amdgcn_mfma_f32_16x16x32_bf16(af, bfr, acc[mt], 0, 0, 0);
            }
        }
        __syncthreads();
    }

    // ---- epilogue: col = posl -> w = wv*16+posl, row = rg*4+reg ----
    const int wout = wv * 16 + posl;
#pragma unroll
    for (int mt = 0; mt < 8; ++mt) {
#pragma unroll
        for (int r = 0; r < 4; ++r) {
            int o = mt * 16 + rg * 4 + r;
            out[((b * OO + o) * HH + h) * WW + wout] = acc[mt][r] + b_def[o];
        }
    }
}

extern "C" void kernel_launch(void* const* d_in, const int* in_sizes, int n_in,
                              void* d_out, int out_size, void* d_ws, size_t ws_size,
                              hipStream_t stream) {
    const float* x     = (const float*)d_in[0];
    const float* w_off = (const float*)d_in[1];
    const float* b_off = (const float*)d_in[2];
    const float* w_def = (const float*)d_in[3];
    const float* b_def = (const float*)d_in[4];
    float* out = (float*)d_out;

    float* offs = (float*)d_ws;                  // 8*18*4096 f   = 2.36 MB
    u16*   xT   = (u16*)(offs + BB * NJ * HW);   // 8*4096*128    = 8.39 MB
    u16*   wT   = xT + (size_t)BB * HW * CC;     // 9*128*128     = 0.29 MB
    u16*   wA   = wT + 9 * OO * CC;              // 32*1152       = 0.07 MB

    k_xT  <<<512, 256, 0, stream>>>(x, xT);
    k_prep<<<576, 256, 0, stream>>>(w_def, w_off, wT, wA);
    k_off <<<512, 256, 0, stream>>>(xT, wA, b_off, offs);
    k_main<<<512, 256, 0, stream>>>(xT, offs, wT, b_def, out);
}

// Round 5
// 139.508 us; speedup vs baseline: 1.1446x; 1.1446x over previous
//
#include <hip/hip_runtime.h>
#include <hip/hip_bf16.h>

#define BB 8
#define CC 128
#define HH 64
#define WW 64
#define OO 128
#define NJ 18
#define HW 4096

typedef unsigned short u16;
typedef unsigned int u32;
typedef __attribute__((ext_vector_type(8))) __bf16 bf16x8;
typedef __attribute__((ext_vector_type(4))) float f32x4;

__device__ __forceinline__ u16 f2bf(float f) {
    u32 u = __float_as_uint(f);
    u += 0x7fffu + ((u >> 16) & 1u);   // RNE
    return (u16)(u >> 16);
}
__device__ __forceinline__ float bflo(u32 u) { return __uint_as_float(u << 16); }
__device__ __forceinline__ float bfhi(u32 u) { return __uint_as_float(u & 0xffff0000u); }
__device__ __forceinline__ u32 pk2bf(float s0, float s1) {
    union { __hip_bfloat162 h; u32 u; } cv;
    cv.h = __float22bfloat162_rn(make_float2(s0, s1));   // v_cvt_pk_bf16_f32
    return cv.u;
}

// ---------------------------------------------------------------------------
// k_xT: x[b][c][hw] fp32 -> xT[b][hw][c] bf16 (channels-last).
// ---------------------------------------------------------------------------
__global__ __launch_bounds__(256)
void k_xT(const float* __restrict__ x, u16* __restrict__ xT) {
    __shared__ float tile[64][129];
    const int t = threadIdx.x;
    const int b = blockIdx.x >> 6;
    const int hw0 = (blockIdx.x & 63) << 6;
    const float* xb = x + (size_t)b * CC * HW + hw0;
    const int tw = t & 63, tc = t >> 6;
#pragma unroll
    for (int r = 0; r < 32; ++r) {
        int c = r * 4 + tc;                 // wave-uniform
        tile[tw][c] = xb[c * HW + tw];
    }
    __syncthreads();
    u16* dst = xT + ((size_t)b * HW + hw0) * CC;
#pragma unroll
    for (int r = 0; r < 4; ++r) {
        int item = t + (r << 8);            // 1024 items = 64 hw x 16 segs
        int seg = item & 15, hw = item >> 4;
        union { u32 d[4]; uint4 v; } p;
#pragma unroll
        for (int i = 0; i < 4; ++i)
            p.d[i] = pk2bf(tile[hw][seg * 8 + 2 * i], tile[hw][seg * 8 + 2 * i + 1]);
        *(uint4*)&dst[hw * CC + seg * 8] = p.v;
    }
}

// ---------------------------------------------------------------------------
// k_prep: wT[kk][o][c] bf16 and wA[j][q*128+c] bf16 (j padded to 32 w/ zeros).
// ---------------------------------------------------------------------------
__global__ void k_prep(const float* __restrict__ w_def,
                       const float* __restrict__ w_off,
                       u16* __restrict__ wT, u16* __restrict__ wA) {
    int idx = blockIdx.x * 256 + threadIdx.x;
    if (idx < 9 * OO * CC) {
        int c = idx & 127, o = (idx >> 7) & 127, kk = idx >> 14;
        wT[idx] = f2bf(w_def[(o * CC + c) * 9 + kk]);
    }
    if (idx < 32 * 1152) {
        int k = idx % 1152, j = idx / 1152;
        int q = k >> 7, c = k & 127;
        wA[idx] = (j < NJ) ? f2bf(w_off[(j * CC + c) * 9 + q]) : (u16)0;
    }
}

// ---------------------------------------------------------------------------
// k_off: offset conv via MFMA, M=18(->32), N=64, K=1152. XCD-swizzled.
// ---------------------------------------------------------------------------
__global__ __launch_bounds__(256, 2)
void k_off(const u16* __restrict__ xT, const u16* __restrict__ wA,
           const float* __restrict__ b_off, float* __restrict__ offs) {
    __shared__ u16 s_x[198 * 128];   // [3 rows x 66 w][128 c] swizzled
    const int t = threadIdx.x, lane = t & 63, wv = t >> 6;
    const int posl = lane & 15, kg = lane >> 4;
    const int b = blockIdx.x & 7, h = blockIdx.x >> 3;

    for (int it = t; it < 3168; it += 256) {
        int seg = it & 15, pix = it >> 4;       // pix = r*66 + wp
        int r = pix / 66, wp = pix - r * 66;
        int y = h - 1 + r, w = wp - 1;
        uint4 v = make_uint4(0, 0, 0, 0);
        if (y >= 0 && y < HH && w >= 0 && w < WW)
            v = *(const uint4*)&xT[((size_t)(b * HW) + y * WW + w) * CC + seg * 8];
        *(uint4*)&s_x[pix * 128 + ((seg ^ (pix & 15)) * 8)] = v;
    }
    __syncthreads();

    f32x4 acc0 = {0.f, 0.f, 0.f, 0.f}, acc1 = {0.f, 0.f, 0.f, 0.f};
    for (int q = 0; q < 9; ++q) {
        int qy = q / 3, qx = q - qy * 3;
        int pix = qy * 66 + (wv * 16 + posl) + qx;
        int prow = pix * 128, pxor = pix & 15;
#pragma unroll
        for (int ki = 0; ki < 4; ++ki) {
            int ks = q * 4 + ki;
            int cidx = ki * 4 + kg;
            bf16x8 bfr = *(const bf16x8*)&s_x[prow + ((cidx ^ pxor) * 8)];
            bf16x8 a0 = *(const bf16x8*)&wA[posl * 1152 + ks * 32 + kg * 8];
            bf16x8 a1 = *(const bf16x8*)&wA[(16 + posl) * 1152 + ks * 32 + kg * 8];
            acc0 = __builtin_amdgcn_mfma_f32_16x16x32_bf16(a0, bfr, acc0, 0, 0, 0);
            acc1 = __builtin_amdgcn_mfma_f32_16x16x32_bf16(a1, bfr, acc1, 0, 0, 0);
        }
    }
    const int pos = wv * 16 + posl;
#pragma unroll
    for (int r = 0; r < 4; ++r) {
        int j = kg * 4 + r;
        offs[(b * NJ + j) * HW + h * WW + pos] = acc0[r] + b_off[j];
    }
#pragma unroll
    for (int r = 0; r < 4; ++r) {
        int j = 16 + kg * 4 + r;
        if (j < NJ) offs[(b * NJ + j) * HW + h * WW + pos] = acc1[r] + b_off[j];
    }
}

// ---------------------------------------------------------------------------
// k_main v5: A = samples (m=pos), B = weights (n=o, DIRECT from global).
// Block = (b, h row): 64 pos x 128 o, 256 threads / 4 waves, grid 512.
// Per kk:
//   gather/interp: thread (pos = t>>2, segsub = t&3) does 4 chunk-sets
//     {segsub+4j}; corner loads put 16 consecutive lanes on the same 4-line
//     256B corner region (<=16 lines/instr). Results -> s_samp (16 KB,
//     XOR-swizzled) = A-fragment store. ONE LDS array, no weight staging.
//   MFMA: wave wv owns o-range [32wv,32wv+32): per ct reads 4 A-frags (LDS)
//     + 2 B-frags (global, 1KB dense 16-line loads, L1/L2-hot) -> 8 MFMAs.
//   2 barriers/kk; LDS total 16 KB -> occupancy VGPR-bound.
// ---------------------------------------------------------------------------
__global__ __launch_bounds__(256, 2)
void k_main(const u16* __restrict__ xT, const float* __restrict__ offs,
            const u16* __restrict__ wT, const float* __restrict__ b_def,
            float* __restrict__ out) {
    __shared__ u16 s_samp[64 * 128];     // 16 KB: [pos][16 chunks XOR-swizzled]

    const int t = threadIdx.x, lane = t & 63, wv = t >> 6;
    const int posl = lane & 15, kg = lane >> 4;
    const int b = blockIdx.x & 7;
    const int h = blockIdx.x >> 3;
    const char* xb = (const char*)xT + (size_t)b * (HW * CC * 2);

    // gather role
    const int gpos = t >> 2;             // 0..63 (= w)
    const int segsub = t & 3;

    f32x4 acc[4][2];
#pragma unroll
    for (int mt = 0; mt < 4; ++mt) {
        acc[mt][0] = (f32x4){0.f, 0.f, 0.f, 0.f};
        acc[mt][1] = (f32x4){0.f, 0.f, 0.f, 0.f};
    }

#pragma unroll 1
    for (int kk = 0; kk < 9; ++kk) {
        // ---- per-thread coords for pos = gpos ----
        int ky = kk / 3, kx = kk - ky * 3;
        float oy = offs[(b * NJ + 2 * kk) * HW + h * WW + gpos];
        float ox = offs[(b * NJ + 2 * kk + 1) * HW + h * WW + gpos];
        float py = (float)(h - 1 + ky) + oy;
        float px = (float)(gpos - 1 + kx) + ox;
        float fy = floorf(py), fx = floorf(px);
        int iy0 = (int)fy, ix0 = (int)fx;
        float wy = py - fy, wx = px - fx;
        int iy1 = iy0 + 1, ix1 = ix0 + 1;
        float my0 = (iy0 >= 0 && iy0 < HH) ? 1.0f : 0.0f;
        float my1 = (iy1 >= 0 && iy1 < HH) ? 1.0f : 0.0f;
        float mx0 = (ix0 >= 0 && ix0 < WW) ? 1.0f : 0.0f;
        float mx1 = (ix1 >= 0 && ix1 < WW) ? 1.0f : 0.0f;
        int iy0c = min(max(iy0, 0), HH - 1), iy1c = min(max(iy1, 0), HH - 1);
        int ix0c = min(max(ix0, 0), WW - 1), ix1c = min(max(ix1, 0), WW - 1);
        float wy1 = 1.0f - wy, wx1 = 1.0f - wx;
        float cwx = my0 * mx0 * wy1 * wx1, cwy = my0 * mx1 * wy1 * wx;
        float cwz = my1 * mx0 * wy * wx1,  cww = my1 * mx1 * wy * wx;
        int cox = (iy0c * WW + ix0c) << 8, coy = (iy0c * WW + ix1c) << 8;
        int coz = (iy1c * WW + ix0c) << 8, cow = (iy1c * WW + ix1c) << 8;

        // ---- gather + interp: chunk-sets {segsub + 4j}, j = 0..3 ----
        const int slotbase = gpos * 128;
        const int pxor = gpos & 15;
#pragma unroll
        for (int j = 0; j < 4; ++j) {
            const int seg = segsub + 4 * j;
            const int sb = seg * 16;       // byte offset within 256B corner
            uint4 q00 = *(const uint4*)(xb + cox + sb);
            uint4 q01 = *(const uint4*)(xb + coy + sb);
            uint4 q10 = *(const uint4*)(xb + coz + sb);
            uint4 q11 = *(const uint4*)(xb + cow + sb);
            const u32* u00 = (const u32*)&q00;
            const u32* u01 = (const u32*)&q01;
            const u32* u10 = (const u32*)&q10;
            const u32* u11 = (const u32*)&q11;
            union { u32 d[4]; uint4 v; } p;
#pragma unroll
            for (int i = 0; i < 4; ++i) {
                float s0 = cwx * bflo(u00[i]) + cwy * bflo(u01[i])
                         + cwz * bflo(u10[i]) + cww * bflo(u11[i]);
                float s1 = cwx * bfhi(u00[i]) + cwy * bfhi(u01[i])
                         + cwz * bfhi(u10[i]) + cww * bfhi(u11[i]);
                p.d[i] = pk2bf(s0, s1);
            }
            *(uint4*)&s_samp[slotbase + ((seg ^ pxor) * 8)] = p.v;
        }
        __syncthreads();

        // ---- MFMA: B-frags (global) prefetched, A-frags from LDS ----
        {
            const int o0 = wv * 32;
            const u16* wkk = wT + kk * (OO * CC);
            bf16x8 wfr[4][2];
#pragma unroll
            for (int ct = 0; ct < 4; ++ct) {
#pragma unroll
                for (int nt = 0; nt < 2; ++nt) {
                    int o = o0 + nt * 16 + posl;
                    wfr[ct][nt] = *(const bf16x8*)&wkk[o * CC + ct * 32 + kg * 8];
                }
            }
#pragma unroll
            for (int ct = 0; ct < 4; ++ct) {
                const int chunk = ct * 4 + kg;
#pragma unroll
                for (int mt = 0; mt < 4; ++mt) {
                    bf16x8 afr = *(const bf16x8*)
                        &s_samp[(mt * 16 + posl) * 128 + ((chunk ^ posl) * 8)];
                    acc[mt][0] = __builtin_amdgcn_mfma_f32_16x16x32_bf16(
                        afr, wfr[ct][0], acc[mt][0], 0, 0, 0);
                    acc[mt][1] = __builtin_amdgcn_mfma_f32_16x16x32_bf16(
                        afr, wfr[ct][1], acc[mt][1], 0, 0, 0);
                }
            }
        }
        __syncthreads();
    }

    // ---- epilogue: D row = pos = mt*16 + kg*4 + r, col = o = wv*32+nt*16+posl
#pragma unroll
    for (int nt = 0; nt < 2; ++nt) {
        const int o = wv * 32 + nt * 16 + posl;
        const float bd = b_def[o];
        float* orow = out + ((b * OO + o) * HH + h) * WW;
#pragma unroll
        for (int mt = 0; mt < 4; ++mt) {
            float4 res;
            res.x = acc[mt][nt][0] + bd;
            res.y = acc[mt][nt][1] + bd;
            res.z = acc[mt][nt][2] + bd;
            res.w = acc[mt][nt][3] + bd;
            *(float4*)&orow[mt * 16 + kg * 4] = res;
        }
    }
}

extern "C" void kernel_launch(void* const* d_in, const int* in_sizes, int n_in,
                              void* d_out, int out_size, void* d_ws, size_t ws_size,
                              hipStream_t stream) {
    const float* x     = (const float*)d_in[0];
    const float* w_off = (const float*)d_in[1];
    const float* b_off = (const float*)d_in[2];
    const float* w_def = (const float*)d_in[3];
    const float* b_def = (const float*)d_in[4];
    float* out = (float*)d_out;

    float* offs = (float*)d_ws;                  // 8*18*4096 f   = 2.36 MB
    u16*   xT   = (u16*)(offs + BB * NJ * HW);   // 8*4096*128    = 8.39 MB
    u16*   wT   = xT + (size_t)BB * HW * CC;     // 9*128*128     = 0.29 MB
    u16*   wA   = wT + 9 * OO * CC;              // 32*1152       = 0.07 MB

    k_xT  <<<512, 256, 0, stream>>>(x, xT);
    k_prep<<<576, 256, 0, stream>>>(w_def, w_off, wT, wA);
    k_off <<<512, 256, 0, stream>>>(xT, wA, b_off, offs);
    k_main<<<512, 256, 0, stream>>>(xT, offs, wT, b_def, out);
}

// Round 6
// 133.806 us; speedup vs baseline: 1.1934x; 1.0426x over previous
//
#include <hip/hip_runtime.h>
#include <hip/hip_bf16.h>

#define BB 8
#define CC 128
#define HH 64
#define WW 64
#define OO 128
#define NJ 18
#define HW 4096

typedef unsigned short u16;
typedef unsigned int u32;
typedef __attribute__((ext_vector_type(8))) __bf16 bf16x8;
typedef __attribute__((ext_vector_type(4))) float f32x4;

__device__ __forceinline__ u16 f2bf(float f) {
    u32 u = __float_as_uint(f);
    u += 0x7fffu + ((u >> 16) & 1u);   // RNE
    return (u16)(u >> 16);
}
__device__ __forceinline__ float bflo(u32 u) { return __uint_as_float(u << 16); }
__device__ __forceinline__ float bfhi(u32 u) { return __uint_as_float(u & 0xffff0000u); }
__device__ __forceinline__ u32 pk2bf(float s0, float s1) {
    union { __hip_bfloat162 h; u32 u; } cv;
    cv.h = __float22bfloat162_rn(make_float2(s0, s1));   // v_cvt_pk_bf16_f32
    return cv.u;
}

// ---------------------------------------------------------------------------
// k_xT: x[b][c][hw] fp32 -> xT[b][hw][c] bf16 (channels-last).
// ---------------------------------------------------------------------------
__global__ __launch_bounds__(256)
void k_xT(const float* __restrict__ x, u16* __restrict__ xT) {
    __shared__ float tile[64][129];
    const int t = threadIdx.x;
    const int b = blockIdx.x >> 6;
    const int hw0 = (blockIdx.x & 63) << 6;
    const float* xb = x + (size_t)b * CC * HW + hw0;
    const int tw = t & 63, tc = t >> 6;
#pragma unroll
    for (int r = 0; r < 32; ++r) {
        int c = r * 4 + tc;                 // wave-uniform
        tile[tw][c] = xb[c * HW + tw];
    }
    __syncthreads();
    u16* dst = xT + ((size_t)b * HW + hw0) * CC;
#pragma unroll
    for (int r = 0; r < 4; ++r) {
        int item = t + (r << 8);            // 1024 items = 64 hw x 16 segs
        int seg = item & 15, hw = item >> 4;
        union { u32 d[4]; uint4 v; } p;
#pragma unroll
        for (int i = 0; i < 4; ++i)
            p.d[i] = pk2bf(tile[hw][seg * 8 + 2 * i], tile[hw][seg * 8 + 2 * i + 1]);
        *(uint4*)&dst[hw * CC + seg * 8] = p.v;
    }
}

// ---------------------------------------------------------------------------
// k_prep: wT[kk][o][c] bf16 and wA[j][q*128+c] bf16 (j padded to 32 w/ zeros).
// ---------------------------------------------------------------------------
__global__ void k_prep(const float* __restrict__ w_def,
                       const float* __restrict__ w_off,
                       u16* __restrict__ wT, u16* __restrict__ wA) {
    int idx = blockIdx.x * 256 + threadIdx.x;
    if (idx < 9 * OO * CC) {
        int c = idx & 127, o = (idx >> 7) & 127, kk = idx >> 14;
        wT[idx] = f2bf(w_def[(o * CC + c) * 9 + kk]);
    }
    if (idx < 32 * 1152) {
        int k = idx % 1152, j = idx / 1152;
        int q = k >> 7, c = k & 127;
        wA[idx] = (j < NJ) ? f2bf(w_off[(j * CC + c) * 9 + q]) : (u16)0;
    }
}

// ---------------------------------------------------------------------------
// k_off: offset conv via MFMA, M=18(->32), N=64, K=1152. XCD-swizzled.
// ---------------------------------------------------------------------------
__global__ __launch_bounds__(256, 2)
void k_off(const u16* __restrict__ xT, const u16* __restrict__ wA,
           const float* __restrict__ b_off, float* __restrict__ offs) {
    __shared__ u16 s_x[198 * 128];   // [3 rows x 66 w][128 c] swizzled
    const int t = threadIdx.x, lane = t & 63, wv = t >> 6;
    const int posl = lane & 15, kg = lane >> 4;
    const int b = blockIdx.x & 7, h = blockIdx.x >> 3;

    for (int it = t; it < 3168; it += 256) {
        int seg = it & 15, pix = it >> 4;       // pix = r*66 + wp
        int r = pix / 66, wp = pix - r * 66;
        int y = h - 1 + r, w = wp - 1;
        uint4 v = make_uint4(0, 0, 0, 0);
        if (y >= 0 && y < HH && w >= 0 && w < WW)
            v = *(const uint4*)&xT[((size_t)(b * HW) + y * WW + w) * CC + seg * 8];
        *(uint4*)&s_x[pix * 128 + ((seg ^ (pix & 15)) * 8)] = v;
    }
    __syncthreads();

    f32x4 acc0 = {0.f, 0.f, 0.f, 0.f}, acc1 = {0.f, 0.f, 0.f, 0.f};
    for (int q = 0; q < 9; ++q) {
        int qy = q / 3, qx = q - qy * 3;
        int pix = qy * 66 + (wv * 16 + posl) + qx;
        int prow = pix * 128, pxor = pix & 15;
#pragma unroll
        for (int ki = 0; ki < 4; ++ki) {
            int ks = q * 4 + ki;
            int cidx = ki * 4 + kg;
            bf16x8 bfr = *(const bf16x8*)&s_x[prow + ((cidx ^ pxor) * 8)];
            bf16x8 a0 = *(const bf16x8*)&wA[posl * 1152 + ks * 32 + kg * 8];
            bf16x8 a1 = *(const bf16x8*)&wA[(16 + posl) * 1152 + ks * 32 + kg * 8];
            acc0 = __builtin_amdgcn_mfma_f32_16x16x32_bf16(a0, bfr, acc0, 0, 0, 0);
            acc1 = __builtin_amdgcn_mfma_f32_16x16x32_bf16(a1, bfr, acc1, 0, 0, 0);
        }
    }
    const int pos = wv * 16 + posl;
#pragma unroll
    for (int r = 0; r < 4; ++r) {
        int j = kg * 4 + r;
        offs[(b * NJ + j) * HW + h * WW + pos] = acc0[r] + b_off[j];
    }
#pragma unroll
    for (int r = 0; r < 4; ++r) {
        int j = 16 + kg * 4 + r;
        if (j < NJ) offs[(b * NJ + j) * HW + h * WW + pos] = acc1[r] + b_off[j];
    }
}

// ---------------------------------------------------------------------------
// k_main v6: software-pipelined kk loop, 1 barrier/kk.
// A = samples (m=pos, LDS double-buffered), B = weights (n=o, direct global).
// Per kk: [issue corner loads kk+1] [weights kk + A-frags + 32 MFMAs — hides
// gather latency] [wait, interp kk+1, store samp[p^1]] [barrier].
// Nothing fresh in flight at the barrier -> vmcnt(0) drain is ~free.
// ---------------------------------------------------------------------------
__global__ __launch_bounds__(256, 2)
void k_main(const u16* __restrict__ xT, const float* __restrict__ offs,
            const u16* __restrict__ wT, const float* __restrict__ b_def,
            float* __restrict__ out) {
    __shared__ u16 s_samp[2][64 * 128];  // 2 x 16 KB, [pos][16 chunks XOR-swz]

    const int t = threadIdx.x, lane = t & 63, wv = t >> 6;
    const int posl = lane & 15, kg = lane >> 4;
    const int b = blockIdx.x & 7;
    const int h = blockIdx.x >> 3;
    const char* xb = (const char*)xT + (size_t)b * (HW * CC * 2);

    // gather role
    const int gpos = t >> 2;             // 0..63 (= w)
    const int segsub = t & 3;
    const int pxor = gpos & 15;
    const int slotbase = gpos * 128;

    auto coords = [&](int kk, float4& cw, int4& co) {
        int ky = kk / 3, kx = kk - ky * 3;
        float oy = offs[(b * NJ + 2 * kk) * HW + h * WW + gpos];
        float ox = offs[(b * NJ + 2 * kk + 1) * HW + h * WW + gpos];
        float py = (float)(h - 1 + ky) + oy;
        float px = (float)(gpos - 1 + kx) + ox;
        float fy = floorf(py), fx = floorf(px);
        int iy0 = (int)fy, ix0 = (int)fx;
        float wy = py - fy, wx = px - fx;
        int iy1 = iy0 + 1, ix1 = ix0 + 1;
        float my0 = (iy0 >= 0 && iy0 < HH) ? 1.0f : 0.0f;
        float my1 = (iy1 >= 0 && iy1 < HH) ? 1.0f : 0.0f;
        float mx0 = (ix0 >= 0 && ix0 < WW) ? 1.0f : 0.0f;
        float mx1 = (ix1 >= 0 && ix1 < WW) ? 1.0f : 0.0f;
        int iy0c = min(max(iy0, 0), HH - 1), iy1c = min(max(iy1, 0), HH - 1);
        int ix0c = min(max(ix0, 0), WW - 1), ix1c = min(max(ix1, 0), WW - 1);
        float wy1 = 1.0f - wy, wx1 = 1.0f - wx;
        cw = make_float4(my0 * mx0 * wy1 * wx1, my0 * mx1 * wy1 * wx,
                         my1 * mx0 * wy  * wx1, my1 * mx1 * wy  * wx);
        co = make_int4((iy0c * WW + ix0c) << 8, (iy0c * WW + ix1c) << 8,
                       (iy1c * WW + ix0c) << 8, (iy1c * WW + ix1c) << 8);
    };
    auto issue_gather = [&](const int4 co, uint4 q[4][4]) {
#pragma unroll
        for (int j = 0; j < 4; ++j) {
            const int sb = (segsub + 4 * j) * 16;
            q[j][0] = *(const uint4*)(xb + co.x + sb);
            q[j][1] = *(const uint4*)(xb + co.y + sb);
            q[j][2] = *(const uint4*)(xb + co.z + sb);
            q[j][3] = *(const uint4*)(xb + co.w + sb);
        }
    };
    auto interp_store = [&](const float4 cw, uint4 q[4][4], int p) {
#pragma unroll
        for (int j = 0; j < 4; ++j) {
            const int seg = segsub + 4 * j;
            const u32* u00 = (const u32*)&q[j][0];
            const u32* u01 = (const u32*)&q[j][1];
            const u32* u10 = (const u32*)&q[j][2];
            const u32* u11 = (const u32*)&q[j][3];
            union { u32 d[4]; uint4 v; } pk;
#pragma unroll
            for (int i = 0; i < 4; ++i) {
                float s0 = cw.x * bflo(u00[i]) + cw.y * bflo(u01[i])
                         + cw.z * bflo(u10[i]) + cw.w * bflo(u11[i]);
                float s1 = cw.x * bfhi(u00[i]) + cw.y * bfhi(u01[i])
                         + cw.z * bfhi(u10[i]) + cw.w * bfhi(u11[i]);
                pk.d[i] = pk2bf(s0, s1);
            }
            *(uint4*)&s_samp[p][slotbase + ((seg ^ pxor) * 8)] = pk.v;
        }
    };

    f32x4 acc[4][2];
#pragma unroll
    for (int mt = 0; mt < 4; ++mt) {
        acc[mt][0] = (f32x4){0.f, 0.f, 0.f, 0.f};
        acc[mt][1] = (f32x4){0.f, 0.f, 0.f, 0.f};
    }

    // ---- prolog: samples for kk=0 ----
    float4 cw; int4 co;
    uint4 q[4][4];
    coords(0, cw, co);
    issue_gather(co, q);
    interp_store(cw, q, 0);
    __syncthreads();

#pragma unroll 1
    for (int kk = 0; kk < 9; ++kk) {
        const int p = kk & 1;

        // ---- issue next kk's corner loads (consumed after MFMA phase) ----
        float4 cwN; int4 coN;
        if (kk < 8) {
            coords(kk + 1, cwN, coN);
            issue_gather(coN, q);
        }

        // ---- MFMA phase on samp[p], weights direct from global ----
        {
            const int o0 = wv * 32;
            const u16* wkk = wT + kk * (OO * CC);
            bf16x8 wfr[4][2];
#pragma unroll
            for (int ct = 0; ct < 4; ++ct) {
#pragma unroll
                for (int nt = 0; nt < 2; ++nt) {
                    int o = o0 + nt * 16 + posl;
                    wfr[ct][nt] = *(const bf16x8*)&wkk[o * CC + ct * 32 + kg * 8];
                }
            }
#pragma unroll
            for (int ct = 0; ct < 4; ++ct) {
                const int chunk = ct * 4 + kg;
#pragma unroll
                for (int mt = 0; mt < 4; ++mt) {
                    bf16x8 afr = *(const bf16x8*)
                        &s_samp[p][(mt * 16 + posl) * 128 + ((chunk ^ posl) * 8)];
                    acc[mt][0] = __builtin_amdgcn_mfma_f32_16x16x32_bf16(
                        afr, wfr[ct][0], acc[mt][0], 0, 0, 0);
                    acc[mt][1] = __builtin_amdgcn_mfma_f32_16x16x32_bf16(
                        afr, wfr[ct][1], acc[mt][1], 0, 0, 0);
                }
            }
        }

        // ---- consume prefetched corners -> samp[p^1]; single barrier ----
        if (kk < 8) {
            interp_store(cwN, q, p ^ 1);
            __syncthreads();
        }
    }

    // ---- epilogue: D row = pos = mt*16 + kg*4 + r, col = o ----
#pragma unroll
    for (int nt = 0; nt < 2; ++nt) {
        const int o = wv * 32 + nt * 16 + posl;
        const float bd = b_def[o];
        float* orow = out + ((b * OO + o) * HH + h) * WW;
#pragma unroll
        for (int mt = 0; mt < 4; ++mt) {
            float4 res;
            res.x = acc[mt][nt][0] + bd;
            res.y = acc[mt][nt][1] + bd;
            res.z = acc[mt][nt][2] + bd;
            res.w = acc[mt][nt][3] + bd;
            *(float4*)&orow[mt * 16 + kg * 4] = res;
        }
    }
}

extern "C" void kernel_launch(void* const* d_in, const int* in_sizes, int n_in,
                              void* d_out, int out_size, void* d_ws, size_t ws_size,
                              hipStream_t stream) {
    const float* x     = (const float*)d_in[0];
    const float* w_off = (const float*)d_in[1];
    const float* b_off = (const float*)d_in[2];
    const float* w_def = (const float*)d_in[3];
    const float* b_def = (const float*)d_in[4];
    float* out = (float*)d_out;

    float* offs = (float*)d_ws;                  // 8*18*4096 f   = 2.36 MB
    u16*   xT   = (u16*)(offs + BB * NJ * HW);   // 8*4096*128    = 8.39 MB
    u16*   wT   = xT + (size_t)BB * HW * CC;     // 9*128*128     = 0.29 MB
    u16*   wA   = wT + 9 * OO * CC;              // 32*1152       = 0.07 MB

    k_xT  <<<512, 256, 0, stream>>>(x, xT);
    k_prep<<<576, 256, 0, stream>>>(w_def, w_off, wT, wA);
    k_off <<<512, 256, 0, stream>>>(xT, wA, b_off, offs);
    k_main<<<512, 256, 0, stream>>>(xT, offs, wT, b_def, out);
}

// Round 7
// 131.746 us; speedup vs baseline: 1.2121x; 1.0156x over previous
//
#include <hip/hip_runtime.h>
#include <hip/hip_bf16.h>

#define BB 8
#define CC 128
#define HH 64
#define WW 64
#define OO 128
#define NJ 18
#define HW 4096

typedef unsigned short u16;
typedef unsigned int u32;
typedef __attribute__((ext_vector_type(8))) __bf16 bf16x8;
typedef __attribute__((ext_vector_type(4))) float f32x4;

__device__ __forceinline__ u16 f2bf(float f) {
    u32 u = __float_as_uint(f);
    u += 0x7fffu + ((u >> 16) & 1u);   // RNE
    return (u16)(u >> 16);
}
__device__ __forceinline__ float bflo(u32 u) { return __uint_as_float(u << 16); }
__device__ __forceinline__ float bfhi(u32 u) { return __uint_as_float(u & 0xffff0000u); }
__device__ __forceinline__ u32 pk2bf(float s0, float s1) {
    union { __hip_bfloat162 h; u32 u; } cv;
    cv.h = __float22bfloat162_rn(make_float2(s0, s1));   // v_cvt_pk_bf16_f32
    return cv.u;
}

// ---------------------------------------------------------------------------
// k_xT: x[b][c][hw] fp32 -> xT[b][hw][c] bf16 (channels-last).
// ---------------------------------------------------------------------------
__global__ __launch_bounds__(256)
void k_xT(const float* __restrict__ x, u16* __restrict__ xT) {
    __shared__ float tile[64][129];
    const int t = threadIdx.x;
    const int b = blockIdx.x >> 6;
    const int hw0 = (blockIdx.x & 63) << 6;
    const float* xb = x + (size_t)b * CC * HW + hw0;
    const int tw = t & 63, tc = t >> 6;
#pragma unroll
    for (int r = 0; r < 32; ++r) {
        int c = r * 4 + tc;                 // wave-uniform
        tile[tw][c] = xb[c * HW + tw];
    }
    __syncthreads();
    u16* dst = xT + ((size_t)b * HW + hw0) * CC;
#pragma unroll
    for (int r = 0; r < 4; ++r) {
        int item = t + (r << 8);            // 1024 items = 64 hw x 16 segs
        int seg = item & 15, hw = item >> 4;
        union { u32 d[4]; uint4 v; } p;
#pragma unroll
        for (int i = 0; i < 4; ++i)
            p.d[i] = pk2bf(tile[hw][seg * 8 + 2 * i], tile[hw][seg * 8 + 2 * i + 1]);
        *(uint4*)&dst[hw * CC + seg * 8] = p.v;
    }
}

// ---------------------------------------------------------------------------
// k_prep: wT[kk][o][c] bf16 and wA[j][q*128+c] bf16 (j padded to 32 w/ zeros).
// ---------------------------------------------------------------------------
__global__ void k_prep(const float* __restrict__ w_def,
                       const float* __restrict__ w_off,
                       u16* __restrict__ wT, u16* __restrict__ wA) {
    int idx = blockIdx.x * 256 + threadIdx.x;
    if (idx < 9 * OO * CC) {
        int c = idx & 127, o = (idx >> 7) & 127, kk = idx >> 14;
        wT[idx] = f2bf(w_def[(o * CC + c) * 9 + kk]);
    }
    if (idx < 32 * 1152) {
        int k = idx % 1152, j = idx / 1152;
        int q = k >> 7, c = k & 127;
        wA[idx] = (j < NJ) ? f2bf(w_off[(j * CC + c) * 9 + q]) : (u16)0;
    }
}

// ---------------------------------------------------------------------------
// k_off: offset conv via MFMA, M=18(->32), N=64, K=1152. XCD-swizzled.
// ---------------------------------------------------------------------------
__global__ __launch_bounds__(256, 2)
void k_off(const u16* __restrict__ xT, const u16* __restrict__ wA,
           const float* __restrict__ b_off, float* __restrict__ offs) {
    __shared__ u16 s_x[198 * 128];   // [3 rows x 66 w][128 c] swizzled
    const int t = threadIdx.x, lane = t & 63, wv = t >> 6;
    const int posl = lane & 15, kg = lane >> 4;
    const int b = blockIdx.x & 7, h = blockIdx.x >> 3;

    for (int it = t; it < 3168; it += 256) {
        int seg = it & 15, pix = it >> 4;       // pix = r*66 + wp
        int r = pix / 66, wp = pix - r * 66;
        int y = h - 1 + r, w = wp - 1;
        uint4 v = make_uint4(0, 0, 0, 0);
        if (y >= 0 && y < HH && w >= 0 && w < WW)
            v = *(const uint4*)&xT[((size_t)(b * HW) + y * WW + w) * CC + seg * 8];
        *(uint4*)&s_x[pix * 128 + ((seg ^ (pix & 15)) * 8)] = v;
    }
    __syncthreads();

    f32x4 acc0 = {0.f, 0.f, 0.f, 0.f}, acc1 = {0.f, 0.f, 0.f, 0.f};
    for (int q = 0; q < 9; ++q) {
        int qy = q / 3, qx = q - qy * 3;
        int pix = qy * 66 + (wv * 16 + posl) + qx;
        int prow = pix * 128, pxor = pix & 15;
#pragma unroll
        for (int ki = 0; ki < 4; ++ki) {
            int ks = q * 4 + ki;
            int cidx = ki * 4 + kg;
            bf16x8 bfr = *(const bf16x8*)&s_x[prow + ((cidx ^ pxor) * 8)];
            bf16x8 a0 = *(const bf16x8*)&wA[posl * 1152 + ks * 32 + kg * 8];
            bf16x8 a1 = *(const bf16x8*)&wA[(16 + posl) * 1152 + ks * 32 + kg * 8];
            acc0 = __builtin_amdgcn_mfma_f32_16x16x32_bf16(a0, bfr, acc0, 0, 0, 0);
            acc1 = __builtin_amdgcn_mfma_f32_16x16x32_bf16(a1, bfr, acc1, 0, 0, 0);
        }
    }
    const int pos = wv * 16 + posl;
#pragma unroll
    for (int r = 0; r < 4; ++r) {
        int j = kg * 4 + r;
        offs[(b * NJ + j) * HW + h * WW + pos] = acc0[r] + b_off[j];
    }
#pragma unroll
    for (int r = 0; r < 4; ++r) {
        int j = 16 + kg * 4 + r;
        if (j < NJ) offs[(b * NJ + j) * HW + h * WW + pos] = acc1[r] + b_off[j];
    }
}

// ---------------------------------------------------------------------------
// k_main v7: register-double-buffered weights + preloaded offsets.
// A = samples (m=pos, LDS dbuf), B = weights (register dbuf wA_/wB_).
// vmcnt is IN-ORDER: MFMAs consume only registers (loaded last iter -> no
// wait); per iter the only vmem waits are interp's gather waits, and those
// gathers had the whole MFMA phase to land. offs preloaded in prolog kills
// the per-iter offs->gather dependent chain. kk fully unrolled so register
// buffers rename away. 1 barrier/kk.
// ---------------------------------------------------------------------------
__global__ __launch_bounds__(256, 2)
void k_main(const u16* __restrict__ xT, const float* __restrict__ offs,
            const u16* __restrict__ wT, const float* __restrict__ b_def,
            float* __restrict__ out) {
    __shared__ u16 s_samp[2][64 * 128];  // 2 x 16 KB, [pos][16 chunks XOR-swz]

    const int t = threadIdx.x, lane = t & 63, wv = t >> 6;
    const int posl = lane & 15, kg = lane >> 4;
    const int b = blockIdx.x & 7;
    const int h = blockIdx.x >> 3;
    const char* xb = (const char*)xT + (size_t)b * (HW * CC * 2);

    // gather role
    const int gpos = t >> 2;             // 0..63 (= w)
    const int segsub = t & 3;
    const int pxor = gpos & 15;
    const int slotbase = gpos * 128;

    // ---- prolog: preload all 18 offset values into registers ----
    float oyv[9], oxv[9];
#pragma unroll
    for (int kk = 0; kk < 9; ++kk) {
        oyv[kk] = offs[(b * NJ + 2 * kk) * HW + h * WW + gpos];
        oxv[kk] = offs[(b * NJ + 2 * kk + 1) * HW + h * WW + gpos];
    }

    auto coords = [&](int kk, float oy, float ox, float4& cw, int4& co) {
        int ky = kk / 3, kx = kk - ky * 3;
        float py = (float)(h - 1 + ky) + oy;
        float px = (float)(gpos - 1 + kx) + ox;
        float fy = floorf(py), fx = floorf(px);
        int iy0 = (int)fy, ix0 = (int)fx;
        float wy = py - fy, wx = px - fx;
        int iy1 = iy0 + 1, ix1 = ix0 + 1;
        float my0 = (iy0 >= 0 && iy0 < HH) ? 1.0f : 0.0f;
        float my1 = (iy1 >= 0 && iy1 < HH) ? 1.0f : 0.0f;
        float mx0 = (ix0 >= 0 && ix0 < WW) ? 1.0f : 0.0f;
        float mx1 = (ix1 >= 0 && ix1 < WW) ? 1.0f : 0.0f;
        int iy0c = min(max(iy0, 0), HH - 1), iy1c = min(max(iy1, 0), HH - 1);
        int ix0c = min(max(ix0, 0), WW - 1), ix1c = min(max(ix1, 0), WW - 1);
        float wy1 = 1.0f - wy, wx1 = 1.0f - wx;
        cw = make_float4(my0 * mx0 * wy1 * wx1, my0 * mx1 * wy1 * wx,
                         my1 * mx0 * wy  * wx1, my1 * mx1 * wy  * wx);
        co = make_int4((iy0c * WW + ix0c) << 8, (iy0c * WW + ix1c) << 8,
                       (iy1c * WW + ix0c) << 8, (iy1c * WW + ix1c) << 8);
    };
    auto issue_gather = [&](const int4 co, uint4 q[4][4]) {
#pragma unroll
        for (int j = 0; j < 4; ++j) {
            const int sb = (segsub + 4 * j) * 16;
            q[j][0] = *(const uint4*)(xb + co.x + sb);
            q[j][1] = *(const uint4*)(xb + co.y + sb);
            q[j][2] = *(const uint4*)(xb + co.z + sb);
            q[j][3] = *(const uint4*)(xb + co.w + sb);
        }
    };
    auto interp_store = [&](const float4 cw, uint4 q[4][4], int p) {
#pragma unroll
        for (int j = 0; j < 4; ++j) {
            const int seg = segsub + 4 * j;
            const u32* u00 = (const u32*)&q[j][0];
            const u32* u01 = (const u32*)&q[j][1];
            const u32* u10 = (const u32*)&q[j][2];
            const u32* u11 = (const u32*)&q[j][3];
            union { u32 d[4]; uint4 v; } pk;
#pragma unroll
            for (int i = 0; i < 4; ++i) {
                float s0 = cw.x * bflo(u00[i]) + cw.y * bflo(u01[i])
                         + cw.z * bflo(u10[i]) + cw.w * bflo(u11[i]);
                float s1 = cw.x * bfhi(u00[i]) + cw.y * bfhi(u01[i])
                         + cw.z * bfhi(u10[i]) + cw.w * bfhi(u11[i]);
                pk.d[i] = pk2bf(s0, s1);
            }
            *(uint4*)&s_samp[p][slotbase + ((seg ^ pxor) * 8)] = pk.v;
        }
    };
    auto load_w = [&](int kk, bf16x8 wfr[4][2]) {
        const u16* wkk = wT + kk * (OO * CC);
        const int o0 = wv * 32;
#pragma unroll
        for (int ct = 0; ct < 4; ++ct)
#pragma unroll
            for (int nt = 0; nt < 2; ++nt) {
                int o = o0 + nt * 16 + posl;
                wfr[ct][nt] = *(const bf16x8*)&wkk[o * CC + ct * 32 + kg * 8];
            }
    };

    f32x4 acc[4][2];
#pragma unroll
    for (int mt = 0; mt < 4; ++mt) {
        acc[mt][0] = (f32x4){0.f, 0.f, 0.f, 0.f};
        acc[mt][1] = (f32x4){0.f, 0.f, 0.f, 0.f};
    }

    // ---- prolog: weights kk=0, samples kk=0 ----
    bf16x8 wA_[4][2], wB_[4][2];
    float4 cw; int4 co;
    uint4 q[4][4];
    load_w(0, wA_);
    coords(0, oyv[0], oxv[0], cw, co);
    issue_gather(co, q);
    interp_store(cw, q, 0);
    __syncthreads();

#pragma unroll
    for (int kk = 0; kk < 9; ++kk) {
        const int p = kk & 1;

        // ---- issue next kk's weight loads (first!) and gathers ----
        if (kk < 8) {
            load_w(kk + 1, wB_);
            coords(kk + 1, oyv[kk + 1], oxv[kk + 1], cw, co);
            issue_gather(co, q);
        }

        // ---- MFMA phase on samp[p]: weights already in registers ----
#pragma unroll
        for (int ct = 0; ct < 4; ++ct) {
            const int chunk = ct * 4 + kg;
#pragma unroll
            for (int mt = 0; mt < 4; ++mt) {
                bf16x8 afr = *(const bf16x8*)
                    &s_samp[p][(mt * 16 + posl) * 128 + ((chunk ^ posl) * 8)];
                acc[mt][0] = __builtin_amdgcn_mfma_f32_16x16x32_bf16(
                    afr, wA_[ct][0], acc[mt][0], 0, 0, 0);
                acc[mt][1] = __builtin_amdgcn_mfma_f32_16x16x32_bf16(
                    afr, wA_[ct][1], acc[mt][1], 0, 0, 0);
            }
        }

        // ---- consume prefetched corners -> samp[p^1]; single barrier ----
        if (kk < 8) {
            interp_store(cw, q, p ^ 1);
            __syncthreads();
        }

        // rotate weight buffers (renamed away by full unroll)
#pragma unroll
        for (int ct = 0; ct < 4; ++ct) {
            wA_[ct][0] = wB_[ct][0];
            wA_[ct][1] = wB_[ct][1];
        }
    }

    // ---- epilogue: D row = pos = mt*16 + kg*4 + r, col = o ----
#pragma unroll
    for (int nt = 0; nt < 2; ++nt) {
        const int o = wv * 32 + nt * 16 + posl;
        const float bd = b_def[o];
        float* orow = out + ((b * OO + o) * HH + h) * WW;
#pragma unroll
        for (int mt = 0; mt < 4; ++mt) {
            float4 res;
            res.x = acc[mt][nt][0] + bd;
            res.y = acc[mt][nt][1] + bd;
            res.z = acc[mt][nt][2] + bd;
            res.w = acc[mt][nt][3] + bd;
            *(float4*)&orow[mt * 16 + kg * 4] = res;
        }
    }
}

extern "C" void kernel_launch(void* const* d_in, const int* in_sizes, int n_in,
                              void* d_out, int out_size, void* d_ws, size_t ws_size,
                              hipStream_t stream) {
    const float* x     = (const float*)d_in[0];
    const float* w_off = (const float*)d_in[1];
    const float* b_off = (const float*)d_in[2];
    const float* w_def = (const float*)d_in[3];
    const float* b_def = (const float*)d_in[4];
    float* out = (float*)d_out;

    float* offs = (float*)d_ws;                  // 8*18*4096 f   = 2.36 MB
    u16*   xT   = (u16*)(offs + BB * NJ * HW);   // 8*4096*128    = 8.39 MB
    u16*   wT   = xT + (size_t)BB * HW * CC;     // 9*128*128     = 0.29 MB
    u16*   wA   = wT + 9 * OO * CC;              // 32*1152       = 0.07 MB

    k_xT  <<<512, 256, 0, stream>>>(x, xT);
    k_prep<<<576, 256, 0, stream>>>(w_def, w_off, wT, wA);
    k_off <<<512, 256, 0, stream>>>(xT, wA, b_off, offs);
    k_main<<<512, 256, 0, stream>>>(xT, offs, wT, b_def, out);
}